// Round 6
// baseline (231.946 us; speedup 1.0000x reference)
//
#include <hip/hip_runtime.h>

// SimpleDialogGNN on MI355X — round 6.
// Identity: msg@W_msg == window(x@W_msg).
// Pipeline:
//   K0 prep          : fused {W transpose+bf16 pack} + {x -> xbf}
//   K1 gemm<1024,0>  : [u|v] = xbf @ wt1^T  (ring-3 LDS, 1 barrier/step, 32x32x16 MFMA)
//   K2 combine       : r = relu(sel(u + window(v) + biases, xbf)) in-place over u
//   K3 gemm<512,1>   : split-K=2 partials P0,P1 = r @ wt_out^T
//   K4 ln_final      : z = x + P0 + P1 + b_out; LayerNorm -> out
//
// GEMM: 128x128 tile, BK=32, XOR-swizzled LDS (slot c of row r holds global
// k-chunk c^((r>>1)&3) -> 0 bank conflicts, verified round 5). Ring-3 buffers
// (48 KiB) let us drop the trailing WAR barrier: with one barrier per step,
// wave drift <= 1 step, and read buf (s%3) never collides with the write
// target ((s+1)%3) of any wave within drift range.
// Wave tile 64x64 = 2x2 of v_mfma_f32_32x32x16_bf16 (8 MFMA/step vs 16).
//
// ws aliasing (54 MiB):
//   region0 [ 0,16M): xbf  -> P1   (xbf read by K1,K2; P1 written by K3)
//   region1 [16,32M): u    -> r (in-place) -> GEMM2 A
//   region2 [32,48M): v    -> P0
//   [48,52M): wt1   [52,54M): wt_out

typedef unsigned short u16;
typedef float floatx16 __attribute__((ext_vector_type(16)));
typedef short shortx8 __attribute__((ext_vector_type(8)));

#define T_ 1024
#define H_ 1024

__device__ __forceinline__ float bf2f(u16 v) {
    return __uint_as_float(((unsigned)v) << 16);
}
__device__ __forceinline__ u16 f2bf(float f) {  // round-to-nearest-even
    unsigned u = __float_as_uint(f);
    return (u16)((u + 0x7fffu + ((u >> 16) & 1u)) >> 16);
}
__device__ __forceinline__ void async16(const void* g, void* l) {
    __builtin_amdgcn_global_load_lds(
        (__attribute__((address_space(1))) void*)g,
        (__attribute__((address_space(3))) void*)l, 16, 0, 0);
}

// ---------------- K0: fused weight transpose-pack + x pack -------------------
// blocks [0,3072): transpose W (wid = bid>>10); blocks [3072,7168): pack x.
__global__ __launch_bounds__(256)
void prep(const float* __restrict__ Wself, const float* __restrict__ Wmsg,
          const float* __restrict__ Wout, const float* __restrict__ x,
          u16* __restrict__ wt1, u16* __restrict__ wt_out, u16* __restrict__ xbf)
{
    __shared__ float s[32][33];
    const int bid = blockIdx.x;
    if (bid < 3072) {
        const int wid = bid >> 10;
        const int rem = bid & 1023;
        const float* src = (wid == 0) ? Wself : ((wid == 1) ? Wmsg : Wout);
        const int n0 = (rem & 31) * 32, k0 = (rem >> 5) * 32;
        const int tx = threadIdx.x & 31, ty = threadIdx.x >> 5;  // 32x8
#pragma unroll
        for (int i = 0; i < 4; ++i) {
            int k = k0 + ty + 8 * i;
            s[ty + 8 * i][tx] = src[(size_t)k * H_ + n0 + tx];
        }
        __syncthreads();
#pragma unroll
        for (int i = 0; i < 4; ++i) {
            int n = n0 + ty + 8 * i;
            u16 v = f2bf(s[tx][ty + 8 * i]);
            if (wid == 0)      wt1[(size_t)n * 1024 + k0 + tx] = v;
            else if (wid == 1) wt1[(size_t)(n + 1024) * 1024 + k0 + tx] = v;
            else               wt_out[(size_t)n * 1024 + k0 + tx] = v;
        }
    } else {
        const size_t i = ((size_t)(bid - 3072) * 256 + threadIdx.x) * 8;
        float4 v0 = *(const float4*)(x + i);
        float4 v1 = *(const float4*)(x + i + 4);
        ushort4 o0, o1;
        o0.x = f2bf(v0.x); o0.y = f2bf(v0.y); o0.z = f2bf(v0.z); o0.w = f2bf(v0.w);
        o1.x = f2bf(v1.x); o1.y = f2bf(v1.y); o1.z = f2bf(v1.z); o1.w = f2bf(v1.w);
        *(ushort4*)(xbf + i) = o0;
        *(ushort4*)(xbf + i + 4) = o1;
    }
}

// ---------------- K1/K3: bf16 MFMA GEMM, ring-3 LDS, 32x32x16 ----------------
// A: M x 1024 row-major bf16; Bt: N x 1024 row-major bf16 (N-major).
// EPI 0: cols [0,1024)->O0, [1024,2048)->O1.  EPI 1: partial -> (z ? O1 : O0).
template <int KLEN, int EPI>
__global__ __launch_bounds__(256)
void gemm_bt(const u16* __restrict__ A, const u16* __restrict__ Bt,
             u16* __restrict__ O0, u16* __restrict__ O1)
{
    __shared__ u16 smem[3 * 8192];  // 3 bufs x (A 4096 u16 | B 4096 u16) = 48 KiB
    const int tid = threadIdx.x;
    const int bn = blockIdx.x * 128;
    const int bm = blockIdx.y * 128;
    const int kb = blockIdx.z * KLEN;
    const int wave = tid >> 6, lane = tid & 63;
    const int wr = wave >> 1, wc = wave & 1;
    const int l32 = lane & 31, hi = lane >> 5;

    // staging (unchanged from round 5): lane tid covers LDS chunk tid (16 B)
    // = row (tid>>2), slot (tid&3); slot c stores global k-chunk c^((row>>1)&3).
    const int srow = tid >> 2;
    const int skc  = (tid & 3) ^ ((srow >> 1) & 3);
    const u16* gA0 = A + (size_t)(bm + srow) * 1024 + kb + skc * 8;
    const u16* gA1 = gA0 + (size_t)64 * 1024;
    const u16* gB0 = Bt + (size_t)(bn + srow) * 1024 + kb + skc * 8;
    const u16* gB1 = gB0 + (size_t)64 * 1024;

    floatx16 acc[2][2];
#pragma unroll
    for (int i = 0; i < 2; ++i)
#pragma unroll
        for (int j = 0; j < 2; ++j)
#pragma unroll
            for (int r = 0; r < 16; ++r)
                acc[i][j][r] = 0.f;

    // fragment LDS offsets (u16 units), swizzle-corrected; s2 = k-slice of 16
    // A-operand layout (32x32x16): m = lane&31, k = (lane>>5)*8 + idx
    int offA[2][2], offB[2][2];
#pragma unroll
    for (int i = 0; i < 2; ++i) {
        const int rowA = wr * 64 + i * 32 + l32;
        const int rowB = wc * 64 + i * 32 + l32;
#pragma unroll
        for (int s2 = 0; s2 < 2; ++s2) {
            offA[i][s2] = rowA * 32 + (((2 * s2 + hi) ^ ((rowA >> 1) & 3)) * 8);
            offB[i][s2] = 4096 + rowB * 32 + (((2 * s2 + hi) ^ ((rowB >> 1) & 3)) * 8);
        }
    }

    auto issue = [&](int s, int q) {
        u16* base = smem + q * 8192 + wave * 512;
        const int k = s * 32;
        async16(gA0 + k, base);
        async16(gA1 + k, base + 2048);
        async16(gB0 + k, base + 4096);
        async16(gB1 + k, base + 4096 + 2048);
    };

    constexpr int NS = KLEN / 32;
    issue(0, 0);
    int qr = 0;
    for (int s = 0; s < NS; ++s) {
        if (s + 1 < NS) {
            const int qw = (qr == 2) ? 0 : qr + 1;
            issue(s + 1, qw);
            asm volatile("s_waitcnt vmcnt(4)" ::: "memory");  // step-s loads landed
        } else {
            asm volatile("s_waitcnt vmcnt(0)" ::: "memory");
        }
        asm volatile("s_barrier" ::: "memory");  // buf qr complete for all waves
        const u16* pb = smem + qr * 8192;
        shortx8 av[2][2], bv[2][2];
#pragma unroll
        for (int i = 0; i < 2; ++i)
#pragma unroll
            for (int s2 = 0; s2 < 2; ++s2) {
                av[i][s2] = *(const shortx8*)(pb + offA[i][s2]);
                bv[i][s2] = *(const shortx8*)(pb + offB[i][s2]);
            }
#pragma unroll
        for (int s2 = 0; s2 < 2; ++s2)
#pragma unroll
            for (int i = 0; i < 2; ++i)
#pragma unroll
                for (int j = 0; j < 2; ++j)
                    acc[i][j] = __builtin_amdgcn_mfma_f32_32x32x16_bf16(
                        av[i][s2], bv[j][s2], acc[i][j], 0, 0, 0);
        qr = (qr == 2) ? 0 : qr + 1;
        // no trailing barrier: ring-3 guarantees the buffer being written next
        // is not the one any (drift<=1) wave is still reading.
    }

    // epilogue — 32x32 C/D mapping (verified m74/m101):
    // col = lane&31, row = (reg&3) + 8*(reg>>2) + 4*(lane>>5)
    u16* O;
    int cbase;
    if (EPI == 0) { O = (bn < 1024) ? O0 : O1; cbase = bn & 1023; }
    else          { O = blockIdx.z ? O1 : O0;  cbase = bn; }
#pragma unroll
    for (int i = 0; i < 2; ++i) {
#pragma unroll
        for (int j = 0; j < 2; ++j) {
            const int col = cbase + wc * 64 + j * 32 + l32;
#pragma unroll
            for (int reg = 0; reg < 16; ++reg) {
                const int row = bm + wr * 64 + i * 32 +
                                (reg & 3) + 8 * (reg >> 2) + 4 * hi;
                O[(size_t)row * 1024 + col] = f2bf(acc[i][j][reg]);
            }
        }
    }
}

// ---------------- K2: combine, no LDS, block-uniform weights ----------------
// grid (T_, B): one block per (t,b) row. w[o] and cnt are block-uniform.
__global__ __launch_bounds__(256)
void combine(u16* __restrict__ uv, const u16* __restrict__ v,
             const u16* __restrict__ xbf, const float* __restrict__ qmask,
             const int* __restrict__ dia_len, const float* __restrict__ b_self,
             const float* __restrict__ b_msg)
{
    const int t = blockIdx.x;
    const int b = blockIdx.y;
    const int tid = threadIdx.x;
    const int dlen = dia_len[b];
    const int c4 = tid * 4;
    const size_t rowg = (size_t)b * T_ + t;

    const float* qb = qmask + (size_t)b * T_ * 2;
    const int spk_t = (qb[t * 2 + 1] > qb[t * 2]) ? 1 : 0;

    float wts[17];
    int cnt = 0;
#pragma unroll
    for (int o = 0; o < 17; ++o) {
        const int idx = t + o - 8;
        if (idx >= 0 && idx < dlen) {
            ++cnt;
            const int spk_i = (qb[idx * 2 + 1] > qb[idx * 2]) ? 1 : 0;
            wts[o] = (spk_i == spk_t) ? 1.0f : 0.5f;
        } else {
            wts[o] = 0.0f;
        }
    }
    const float inv = 1.0f / (float)(cnt > 0 ? cnt : 1);

    float a0 = 0.f, a1 = 0.f, a2 = 0.f, a3 = 0.f;
#pragma unroll
    for (int o = 0; o < 17; ++o) {
        if (wts[o] != 0.0f) {  // block-uniform branch
            const float w = wts[o] * inv;
            ushort4 vv = *(const ushort4*)(v + (rowg + (o - 8)) * 1024 + c4);
            a0 += w * bf2f(vv.x); a1 += w * bf2f(vv.y);
            a2 += w * bf2f(vv.z); a3 += w * bf2f(vv.w);
        }
    }

    float4 bs;
    {
        float4 b1 = *(const float4*)(b_self + c4);
        float4 b2 = *(const float4*)(b_msg + c4);
        bs.x = b1.x + b2.x; bs.y = b1.y + b2.y;
        bs.z = b1.z + b2.z; bs.w = b1.w + b2.w;
    }

    ushort4 u4 = *(const ushort4*)(uv + rowg * 1024 + c4);
    ushort4 xb = *(const ushort4*)(xbf + rowg * 1024 + c4);
    const bool sel = (t < dlen);
    float h0 = bf2f(u4.x) + bs.x + a0;
    float h1 = bf2f(u4.y) + bs.y + a1;
    float h2 = bf2f(u4.z) + bs.z + a2;
    float h3 = bf2f(u4.w) + bs.w + a3;
    ushort4 outv;
    outv.x = f2bf(fmaxf(sel ? h0 : bf2f(xb.x), 0.f));
    outv.y = f2bf(fmaxf(sel ? h1 : bf2f(xb.y), 0.f));
    outv.z = f2bf(fmaxf(sel ? h2 : bf2f(xb.z), 0.f));
    outv.w = f2bf(fmaxf(sel ? h3 : bf2f(xb.w), 0.f));
    *(ushort4*)(uv + rowg * 1024 + c4) = outv;  // in-place over u
}

// ---------------- K4: z = x + P0 + P1 + b_out; LayerNorm --------------------
__global__ __launch_bounds__(256)
void ln_final(const u16* __restrict__ P0, const u16* __restrict__ P1,
              const float* __restrict__ x, const float* __restrict__ b_out,
              const float* __restrict__ gamma, const float* __restrict__ beta,
              float* __restrict__ out)
{
    const int row = blockIdx.x;
    const int tid = threadIdx.x;
    const size_t base = (size_t)row * H_ + tid * 4;
    float4 xv = *(const float4*)(x + base);
    ushort4 p0 = *(const ushort4*)(P0 + base);
    ushort4 p1 = *(const ushort4*)(P1 + base);
    float4 bo = *(const float4*)(b_out + tid * 4);
    float4 v;
    v.x = xv.x + bf2f(p0.x) + bf2f(p1.x) + bo.x;
    v.y = xv.y + bf2f(p0.y) + bf2f(p1.y) + bo.y;
    v.z = xv.z + bf2f(p0.z) + bf2f(p1.z) + bo.z;
    v.w = xv.w + bf2f(p0.w) + bf2f(p1.w) + bo.w;
    float s = v.x + v.y + v.z + v.w;
    float q = v.x * v.x + v.y * v.y + v.z * v.z + v.w * v.w;
#pragma unroll
    for (int off = 32; off > 0; off >>= 1) {
        s += __shfl_down(s, off);
        q += __shfl_down(q, off);
    }
    __shared__ float ps[4], pq[4];
    const int wave = tid >> 6, lane = tid & 63;
    if (lane == 0) { ps[wave] = s; pq[wave] = q; }
    __syncthreads();
    const float S = ps[0] + ps[1] + ps[2] + ps[3];
    const float Q = pq[0] + pq[1] + pq[2] + pq[3];
    const float mean = S * (1.0f / 1024.0f);
    const float var = Q * (1.0f / 1024.0f) - mean * mean;
    const float inv = rsqrtf(var + 1e-5f);
    float4 g = *(const float4*)(gamma + tid * 4);
    float4 bt = *(const float4*)(beta + tid * 4);
    float4 o;
    o.x = g.x * (v.x - mean) * inv + bt.x;
    o.y = g.y * (v.y - mean) * inv + bt.y;
    o.z = g.z * (v.z - mean) * inv + bt.z;
    o.w = g.w * (v.w - mean) * inv + bt.w;
    *(float4*)(out + base) = o;
}

// ---------------- launcher ---------------------------------------------------
extern "C" void kernel_launch(void* const* d_in, const int* in_sizes, int n_in,
                              void* d_out, int out_size, void* d_ws, size_t ws_size,
                              hipStream_t stream)
{
    (void)in_sizes; (void)n_in; (void)out_size; (void)ws_size;
    const float* x       = (const float*)d_in[0];
    const float* qmask   = (const float*)d_in[1];
    const int*   dia_len = (const int*)d_in[2];
    const float* W_msg   = (const float*)d_in[5];
    const float* b_msg   = (const float*)d_in[6];
    const float* W_self  = (const float*)d_in[7];
    const float* b_self  = (const float*)d_in[8];
    const float* W_out   = (const float*)d_in[9];
    const float* b_out   = (const float*)d_in[10];
    const float* gamma   = (const float*)d_in[11];
    const float* beta    = (const float*)d_in[12];
    float* out = (float*)d_out;

    char* ws = (char*)d_ws;
    u16* region0 = (u16*)ws;                           // xbf -> P1
    u16* region1 = (u16*)(ws + (size_t)(16u << 20));   // u   -> r (in-place)
    u16* region2 = (u16*)(ws + (size_t)(32u << 20));   // v   -> P0
    u16* wt1     = (u16*)(ws + (size_t)(48u << 20));   // 4 MiB
    u16* wt_out  = (u16*)(ws + (size_t)(52u << 20));   // 2 MiB

    prep<<<dim3(7168), 256, 0, stream>>>(W_self, W_msg, W_out, x,
                                         wt1, wt_out, region0);
    gemm_bt<1024, 0><<<dim3(16, 64, 1), 256, 0, stream>>>(region0, wt1,
                                                          region1, region2);
    combine<<<dim3(T_, 8), 256, 0, stream>>>(region1, region2, region0, qmask,
                                             dia_len, b_self, b_msg);
    gemm_bt<512, 1><<<dim3(8, 64, 2), 256, 0, stream>>>(region1, wt_out,
                                                        region2, region0);
    ln_final<<<dim3(8192), 256, 0, stream>>>(region2, region0, x, b_out,
                                             gamma, beta, out);
}